// Round 1
// baseline (131.135 us; speedup 1.0000x reference)
//
#include <hip/hip_runtime.h>

typedef unsigned short u16;
typedef __attribute__((ext_vector_type(8))) short short8;
typedef __attribute__((ext_vector_type(4))) float f32x4;

#define GL2LDS16(src, dst) __builtin_amdgcn_global_load_lds( \
    (const __attribute__((address_space(1))) void*)(src),    \
    (__attribute__((address_space(3))) void*)(dst), 16, 0, 0)

__device__ __forceinline__ u16 f2bf(float f) {
  union { float f; unsigned u; } v; v.f = f;
  unsigned r = v.u + 0x7fffu + ((v.u >> 16) & 1u);
  return (u16)(r >> 16);
}
__device__ __forceinline__ float bf2f(u16 h) {
  union { unsigned u; float f; } v; v.u = ((unsigned)h) << 16; return v.f;
}

// ---------------- fp32 -> bf16 convert (vectorized) ----------------
__global__ void k_cvt_bf16(const float* __restrict__ in, u16* __restrict__ out, int n8) {
  int i = blockIdx.x * 256 + threadIdx.x;
  if (i >= n8) return;
  const float4* p = (const float4*)in + 2 * (size_t)i;
  float4 a = p[0], b = p[1];
  short8 o;
  o[0] = (short)f2bf(a.x); o[1] = (short)f2bf(a.y); o[2] = (short)f2bf(a.z); o[3] = (short)f2bf(a.w);
  o[4] = (short)f2bf(b.x); o[5] = (short)f2bf(b.y); o[6] = (short)f2bf(b.z); o[7] = (short)f2bf(b.w);
  ((short8*)out)[i] = o;
}

// ------------- fp32 [z][R][C] -> bf16 [z][C][R] (transpose+convert) -------------
__global__ void k_transpose_cvt(const float* __restrict__ in, u16* __restrict__ out, int R, int C) {
  __shared__ float tile[32][33];
  size_t zoff = (size_t)blockIdx.z * R * C;
  in += zoff; out += zoff;
  int c0 = blockIdx.x * 32, r0 = blockIdx.y * 32;
  int tx = threadIdx.x, ty = threadIdx.y;
#pragma unroll
  for (int i = ty; i < 32; i += 8)
    tile[i][tx] = in[(size_t)(r0 + i) * C + (c0 + tx)];
  __syncthreads();
#pragma unroll
  for (int i = ty; i < 32; i += 8)
    out[(size_t)(c0 + i) * R + (r0 + tx)] = f2bf(tile[tx][i]);
}

// ---------------- gates: fp32 matmul + softmax, one wave per row ----------------
template <int NG, int KD>
__device__ __forceinline__ void gate_row(const float* __restrict__ x, const float* __restrict__ W,
                                         const float* __restrict__ bv, float* __restrict__ out,
                                         int b, int lane) {
  float s[NG];
#pragma unroll
  for (int j = 0; j < NG; ++j) s[j] = 0.f;
  const float* xr = x + (size_t)b * KD;
  for (int k = lane; k < KD; k += 64) {
    float xv = xr[k];
    const float* wr = W + (size_t)k * NG;
#pragma unroll
    for (int j = 0; j < NG; ++j) s[j] += xv * wr[j];
  }
#pragma unroll
  for (int off = 32; off >= 1; off >>= 1) {
#pragma unroll
    for (int j = 0; j < NG; ++j) s[j] += __shfl_xor(s[j], off, 64);
  }
#pragma unroll
  for (int j = 0; j < NG; ++j) s[j] += bv[j];
  float m = s[0];
#pragma unroll
  for (int j = 1; j < NG; ++j) m = fmaxf(m, s[j]);
  float tot = 0.f;
#pragma unroll
  for (int j = 0; j < NG; ++j) { s[j] = __expf(s[j] - m); tot += s[j]; }
  float inv = 1.f / tot;
  if (lane == 0) {
#pragma unroll
    for (int j = 0; j < NG; ++j) out[(size_t)b * NG + j] = s[j] * inv;
  }
}

__global__ void k_gates(const float* __restrict__ xf, const float* __restrict__ x1,
                        const float* __restrict__ x2,
                        const float* __restrict__ gshW, const float* __restrict__ gshB,
                        const float* __restrict__ g1W, const float* __restrict__ g1B,
                        const float* __restrict__ g2W, const float* __restrict__ g2B,
                        float* __restrict__ gsh, float* __restrict__ g1, float* __restrict__ g2) {
  int b = blockIdx.x, lane = threadIdx.x;
  gate_row<12, 1024>(xf, gshW, gshB, gsh, b, lane);
  gate_row<8, 512>(x1, g1W, g1B, g1, b, lane);
  gate_row<8, 512>(x2, g2W, g2B, g2, b, lane);
}

// ---------------- grouped GEMM: C = relu(A @ B^T + bias), bf16 in/out ----------------
// A: [4096][K] bf16 row-major; BT: [N][K] bf16 row-major; C: [4096][N] bf16.
// 128x128 tile, BK=32, 4 waves, 16x16x32 bf16 MFMA (m97 structure).
struct GemmDesc {
  const u16* A;
  const u16* BT;
  const float* bias;
  u16* C;
  int K;
  int N;
};
struct GemmArgs { GemmDesc d[12]; };

__global__ __launch_bounds__(256, 2) void k_gemm(GemmArgs args) {
  GemmDesc g = args.d[blockIdx.y];
  const int K = g.K, N = g.N;
  const int row0 = (blockIdx.x & 31) << 7;   // 32 row tiles of 128 (M=4096)
  const int col0 = (blockIdx.x >> 5) << 7;   // N/128 col tiles

  __shared__ __align__(16) u16 As[128 * 32];
  __shared__ __align__(16) u16 Bs[128 * 32];

  const int lane = threadIdx.x & 63;
  const int wave = threadIdx.x >> 6;
  const int wr = (wave >> 1) << 6;           // wave row origin within tile
  const int wc = (wave & 1) << 6;            // wave col origin
  const int lrow = lane & 15;
  const int kgrp = (lane >> 4) << 3;         // k offset of this lane's fragment

  f32x4 acc[4][4];
#pragma unroll
  for (int m = 0; m < 4; ++m)
#pragma unroll
    for (int n = 0; n < 4; ++n)
      acc[m][n] = (f32x4){0.f, 0.f, 0.f, 0.f};

  for (int k0 = 0; k0 < K; k0 += 32) {
    // stage A,B tiles (128x32 bf16 = 8KB each) via global_load_lds width=16
#pragma unroll
    for (int i = 0; i < 2; ++i) {
      const int cb = (i * 4 + wave) * 64;    // wave-uniform chunk base (16B units)
      const int c = cb + lane;
      const int r = c >> 2;                  // 4 chunks per 64B row
      const int kk = (c & 3) << 3;
      GL2LDS16(g.A + (size_t)(row0 + r) * K + (k0 + kk), &As[cb * 8]);
      GL2LDS16(g.BT + (size_t)(col0 + r) * K + (k0 + kk), &Bs[cb * 8]);
    }
    __syncthreads();

    short8 a[4], b[4];
#pragma unroll
    for (int m = 0; m < 4; ++m)
      a[m] = *(const short8*)&As[(wr + (m << 4) + lrow) * 32 + kgrp];
#pragma unroll
    for (int n = 0; n < 4; ++n)
      b[n] = *(const short8*)&Bs[(wc + (n << 4) + lrow) * 32 + kgrp];
#pragma unroll
    for (int m = 0; m < 4; ++m)
#pragma unroll
      for (int n = 0; n < 4; ++n)
        acc[m][n] = __builtin_amdgcn_mfma_f32_16x16x32_bf16(a[m], b[n], acc[m][n], 0, 0, 0);
    __syncthreads();
  }

  // epilogue: bias + relu + bf16 store. C/D map: col=lane&15, row=(lane>>4)*4+j
  const int rbase = (lane >> 4) << 2;
#pragma unroll
  for (int n = 0; n < 4; ++n) {
    const int gc = col0 + wc + (n << 4) + lrow;
    const float bv = g.bias[gc];
#pragma unroll
    for (int m = 0; m < 4; ++m) {
      const int gr = row0 + wr + (m << 4) + rbase;
#pragma unroll
      for (int j = 0; j < 4; ++j) {
        float o = acc[m][n][j] + bv;
        o = fmaxf(o, 0.f);
        g.C[(size_t)(gr + j) * N + gc] = f2bf(o);
      }
    }
  }
}

// ---------------- gated reduce: 3 outputs from 12 expert outputs ----------------
// OutB: [12][4096][256] bf16, slots 0-3=t1, 4-7=t2, 8-11=shared.
__global__ void k_reduce(const u16* __restrict__ OutB, const float* __restrict__ gsh,
                         const float* __restrict__ g1, const float* __restrict__ g2,
                         float* __restrict__ out) {
  int t = blockIdx.x * 256 + threadIdx.x;
  int b = t >> 5;
  int c0 = (t & 31) << 3;
  float wsh[12], w1[8], w2[8];
#pragma unroll
  for (int j = 0; j < 12; ++j) wsh[j] = gsh[(size_t)b * 12 + j];
#pragma unroll
  for (int j = 0; j < 8; ++j) { w1[j] = g1[(size_t)b * 8 + j]; w2[j] = g2[(size_t)b * 8 + j]; }
  float ash[8] = {0, 0, 0, 0, 0, 0, 0, 0};
  float a1[8] = {0, 0, 0, 0, 0, 0, 0, 0};
  float a2[8] = {0, 0, 0, 0, 0, 0, 0, 0};
#pragma unroll
  for (int e = 0; e < 12; ++e) {
    short8 v = *(const short8*)&OutB[((size_t)e * 4096 + b) * 256 + c0];
    float f[8];
#pragma unroll
    for (int i = 0; i < 8; ++i) f[i] = bf2f((u16)v[i]);
#pragma unroll
    for (int i = 0; i < 8; ++i) ash[i] += wsh[e] * f[i];
    if (e < 4) {
#pragma unroll
      for (int i = 0; i < 8; ++i) a1[i] += w1[e] * f[i];
    } else if (e < 8) {
#pragma unroll
      for (int i = 0; i < 8; ++i) a2[i] += w2[e - 4] * f[i];
    } else {
#pragma unroll
      for (int i = 0; i < 8; ++i) a1[i] += w1[e - 4] * f[i];
#pragma unroll
      for (int i = 0; i < 8; ++i) a2[i] += w2[e - 4] * f[i];
    }
  }
  size_t base = (size_t)b * 256 + c0;
  float4* o;
  o = (float4*)(out + base);
  o[0] = make_float4(ash[0], ash[1], ash[2], ash[3]);
  o[1] = make_float4(ash[4], ash[5], ash[6], ash[7]);
  o = (float4*)(out + 4096ull * 256 + base);
  o[0] = make_float4(a1[0], a1[1], a1[2], a1[3]);
  o[1] = make_float4(a1[4], a1[5], a1[6], a1[7]);
  o = (float4*)(out + 2ull * 4096 * 256 + base);
  o[0] = make_float4(a2[0], a2[1], a2[2], a2[3]);
  o[1] = make_float4(a2[4], a2[5], a2[6], a2[7]);
}

extern "C" void kernel_launch(void* const* d_in, const int* in_sizes, int n_in,
                              void* d_out, int out_size, void* d_ws, size_t ws_size,
                              hipStream_t stream) {
  const float* x_full = (const float*)d_in[0];
  const float* x_t1 = (const float*)d_in[1];
  const float* x_t2 = (const float*)d_in[2];
  const float* sh_W1 = (const float*)d_in[3];
  const float* sh_b1 = (const float*)d_in[4];
  const float* sh_W2 = (const float*)d_in[5];
  const float* sh_b2 = (const float*)d_in[6];
  const float* t1_W1 = (const float*)d_in[7];
  const float* t1_b1 = (const float*)d_in[8];
  const float* t1_W2 = (const float*)d_in[9];
  const float* t1_b2 = (const float*)d_in[10];
  const float* t2_W1 = (const float*)d_in[11];
  const float* t2_b1 = (const float*)d_in[12];
  const float* t2_W2 = (const float*)d_in[13];
  const float* t2_b2 = (const float*)d_in[14];
  const float* gsh_W = (const float*)d_in[15];
  const float* gsh_b = (const float*)d_in[16];
  const float* g1_W = (const float*)d_in[17];
  const float* g1_b = (const float*)d_in[18];
  const float* g2_W = (const float*)d_in[19];
  const float* g2_b = (const float*)d_in[20];

  char* ws = (char*)d_ws;
  size_t off = 0;
  auto alloc = [&](size_t bytes) -> void* {
    void* p = ws + off;
    off += (bytes + 255) & ~(size_t)255;
    return p;
  };
  u16* xf_b = (u16*)alloc(4096ull * 1024 * 2);
  u16* x1_b = (u16*)alloc(4096ull * 512 * 2);
  u16* x2_b = (u16*)alloc(4096ull * 512 * 2);
  u16* w1t_t1 = (u16*)alloc(4ull * 512 * 512 * 2);   // [e][HID=512][K=512]
  u16* w1t_t2 = (u16*)alloc(4ull * 512 * 512 * 2);
  u16* w1t_sh = (u16*)alloc(4ull * 512 * 1024 * 2);  // [e][512][1024]
  u16* w2t = (u16*)alloc(12ull * 256 * 512 * 2);     // [slot][OUT=256][HID=512]
  u16* H = (u16*)alloc(12ull * 4096 * 512 * 2);      // hidden, slots: t1 0-3, t2 4-7, sh 8-11
  u16* OutB = (u16*)alloc(12ull * 4096 * 256 * 2);   // expert outputs, same slot order
  float* gshv = (float*)alloc(4096ull * 12 * 4);
  float* g1v = (float*)alloc(4096ull * 8 * 4);
  float* g2v = (float*)alloc(4096ull * 8 * 4);

  // --- input conversions ---
  k_cvt_bf16<<<4096 * 1024 / 8 / 256, 256, 0, stream>>>(x_full, xf_b, 4096 * 1024 / 8);
  k_cvt_bf16<<<4096 * 512 / 8 / 256, 256, 0, stream>>>(x_t1, x1_b, 4096 * 512 / 8);
  k_cvt_bf16<<<4096 * 512 / 8 / 256, 256, 0, stream>>>(x_t2, x2_b, 4096 * 512 / 8);

  // --- weight transpose+convert: [K][N] fp32 -> [N][K] bf16 ---
  k_transpose_cvt<<<dim3(16, 16, 4), dim3(32, 8), 0, stream>>>(t1_W1, w1t_t1, 512, 512);
  k_transpose_cvt<<<dim3(16, 16, 4), dim3(32, 8), 0, stream>>>(t2_W1, w1t_t2, 512, 512);
  k_transpose_cvt<<<dim3(16, 32, 4), dim3(32, 8), 0, stream>>>(sh_W1, w1t_sh, 1024, 512);
  k_transpose_cvt<<<dim3(8, 16, 4), dim3(32, 8), 0, stream>>>(t1_W2, w2t, 512, 256);
  k_transpose_cvt<<<dim3(8, 16, 4), dim3(32, 8), 0, stream>>>(t2_W2, w2t + 4ull * 256 * 512, 512, 256);
  k_transpose_cvt<<<dim3(8, 16, 4), dim3(32, 8), 0, stream>>>(sh_W2, w2t + 8ull * 256 * 512, 512, 256);

  // --- gates (fp32) ---
  k_gates<<<4096, 64, 0, stream>>>(x_full, x_t1, x_t2, gsh_W, gsh_b, g1_W, g1_b, g2_W, g2_b,
                                   gshv, g1v, g2v);

  // --- GEMM1: H = relu(x @ W1 + b1), grouped over 12 experts ---
  GemmArgs ga1;
  for (int e = 0; e < 4; ++e) {
    // y=0..3: shared experts (K=1024) first for tail balance
    ga1.d[e] = GemmDesc{xf_b, w1t_sh + (size_t)e * 512 * 1024, sh_b1 + e * 512,
                        H + (size_t)(8 + e) * 4096 * 512, 1024, 512};
    ga1.d[4 + e] = GemmDesc{x1_b, w1t_t1 + (size_t)e * 512 * 512, t1_b1 + e * 512,
                            H + (size_t)e * 4096 * 512, 512, 512};
    ga1.d[8 + e] = GemmDesc{x2_b, w1t_t2 + (size_t)e * 512 * 512, t2_b1 + e * 512,
                            H + (size_t)(4 + e) * 4096 * 512, 512, 512};
  }
  k_gemm<<<dim3(128, 12), 256, 0, stream>>>(ga1);

  // --- GEMM2: Out = relu(H @ W2 + b2), grouped over 12 experts ---
  GemmArgs ga2;
  for (int e = 0; e < 12; ++e) {
    const float* bias = (e < 4) ? (t1_b2 + e * 256)
                      : (e < 8) ? (t2_b2 + (e - 4) * 256)
                                : (sh_b2 + (e - 8) * 256);
    ga2.d[e] = GemmDesc{H + (size_t)e * 4096 * 512, w2t + (size_t)e * 256 * 512, bias,
                        OutB + (size_t)e * 4096 * 256, 512, 256};
  }
  k_gemm<<<dim3(64, 12), 256, 0, stream>>>(ga2);

  // --- gated reduce -> d_out (out_sh | out1 | out2), fp32 ---
  k_reduce<<<512, 256, 0, stream>>>(OutB, gshv, g1v, g2v, (float*)d_out);
}

// Round 2
// 117.864 us; speedup vs baseline: 1.1126x; 1.1126x over previous
//
#include <hip/hip_runtime.h>

typedef unsigned short u16;
typedef __attribute__((ext_vector_type(8))) short short8;
typedef __attribute__((ext_vector_type(4))) float f32x4;

#define GL2LDS16(src, dst) __builtin_amdgcn_global_load_lds( \
    (const __attribute__((address_space(1))) void*)(src),    \
    (__attribute__((address_space(3))) void*)(dst), 16, 0, 0)

__device__ __forceinline__ u16 f2bf(float f) {
  union { float f; unsigned u; } v; v.f = f;
  unsigned r = v.u + 0x7fffu + ((v.u >> 16) & 1u);
  return (u16)(r >> 16);
}
__device__ __forceinline__ float bf2f(u16 h) {
  union { unsigned u; float f; } v; v.u = ((unsigned)h) << 16; return v.f;
}

// ---------------- gates + x->bf16 conversion, one wave per row ----------------
__global__ void k_gates_cvt(const float* __restrict__ xf, const float* __restrict__ x1,
                            const float* __restrict__ x2,
                            const float* __restrict__ gshW, const float* __restrict__ gshB,
                            const float* __restrict__ g1W, const float* __restrict__ g1B,
                            const float* __restrict__ g2W, const float* __restrict__ g2B,
                            u16* __restrict__ xfb, u16* __restrict__ x1b, u16* __restrict__ x2b,
                            float* __restrict__ gsh, float* __restrict__ g1o,
                            float* __restrict__ g2o) {
  const int b = blockIdx.x, lane = threadIdx.x;
  // shared gate over x_full (D=1024, 12 outputs) + bf16 cast
  float s[12];
#pragma unroll
  for (int j = 0; j < 12; ++j) s[j] = 0.f;
  {
    const float* xr = xf + (size_t)b * 1024;
    u16* xw = xfb + (size_t)b * 1024;
    for (int k = lane; k < 1024; k += 64) {
      float v = xr[k];
      xw[k] = f2bf(v);
      const float* wr = gshW + (size_t)k * 12;
#pragma unroll
      for (int j = 0; j < 12; ++j) s[j] += v * wr[j];
    }
  }
  // task gates over x1/x2 (D=512, 8 outputs each) + bf16 cast
  float u[8], w[8];
#pragma unroll
  for (int j = 0; j < 8; ++j) { u[j] = 0.f; w[j] = 0.f; }
  {
    const float* xr1 = x1 + (size_t)b * 512;
    const float* xr2 = x2 + (size_t)b * 512;
    u16* xw1 = x1b + (size_t)b * 512;
    u16* xw2 = x2b + (size_t)b * 512;
    for (int k = lane; k < 512; k += 64) {
      float v1 = xr1[k], v2 = xr2[k];
      xw1[k] = f2bf(v1); xw2[k] = f2bf(v2);
      const float* w1r = g1W + (size_t)k * 8;
      const float* w2r = g2W + (size_t)k * 8;
#pragma unroll
      for (int j = 0; j < 8; ++j) { u[j] += v1 * w1r[j]; w[j] += v2 * w2r[j]; }
    }
  }
#pragma unroll
  for (int off = 32; off >= 1; off >>= 1) {
#pragma unroll
    for (int j = 0; j < 12; ++j) s[j] += __shfl_xor(s[j], off, 64);
#pragma unroll
    for (int j = 0; j < 8; ++j) { u[j] += __shfl_xor(u[j], off, 64); w[j] += __shfl_xor(w[j], off, 64); }
  }
  if (lane == 0) {
    // softmax for shared gate
    float m = -1e30f, tot = 0.f;
#pragma unroll
    for (int j = 0; j < 12; ++j) { s[j] += gshB[j]; m = fmaxf(m, s[j]); }
#pragma unroll
    for (int j = 0; j < 12; ++j) { s[j] = __expf(s[j] - m); tot += s[j]; }
    float inv = 1.f / tot;
#pragma unroll
    for (int j = 0; j < 12; ++j) gsh[(size_t)b * 12 + j] = s[j] * inv;
    m = -1e30f; tot = 0.f;
#pragma unroll
    for (int j = 0; j < 8; ++j) { u[j] += g1B[j]; m = fmaxf(m, u[j]); }
#pragma unroll
    for (int j = 0; j < 8; ++j) { u[j] = __expf(u[j] - m); tot += u[j]; }
    inv = 1.f / tot;
#pragma unroll
    for (int j = 0; j < 8; ++j) g1o[(size_t)b * 8 + j] = u[j] * inv;
    m = -1e30f; tot = 0.f;
#pragma unroll
    for (int j = 0; j < 8; ++j) { w[j] += g2B[j]; m = fmaxf(m, w[j]); }
#pragma unroll
    for (int j = 0; j < 8; ++j) { w[j] = __expf(w[j] - m); tot += w[j]; }
    inv = 1.f / tot;
#pragma unroll
    for (int j = 0; j < 8; ++j) g2o[(size_t)b * 8 + j] = w[j] * inv;
  }
}

// ------------- merged weight transpose+convert: fp32 [z][R][C] -> bf16 [z][C][R] -------------
struct TD { const float* src; u16* dst; int lgTps; int lgNtx; int R; int C; int tileBase; };
struct TArgs { TD d[6]; };

__global__ void k_transpose_all(TArgs ta) {
  __shared__ float tile[32][33];
  const int x = blockIdx.x;
  int di = 0;
#pragma unroll
  for (int i = 1; i < 6; ++i)
    if (x >= ta.d[i].tileBase) di = i;
  TD d = ta.d[di];
  const int local = x - d.tileBase;
  const int slice = local >> d.lgTps;
  const int ti = local & ((1 << d.lgTps) - 1);
  const int tx = ti & ((1 << d.lgNtx) - 1);
  const int ty = ti >> d.lgNtx;
  const float* src = d.src + (size_t)slice * d.R * d.C;
  u16* dst = d.dst + (size_t)slice * d.R * d.C;
  const int c0 = tx * 32, r0 = ty * 32;
  const int ttx = threadIdx.x, tty = threadIdx.y;
#pragma unroll
  for (int i = tty; i < 32; i += 8)
    tile[i][ttx] = src[(size_t)(r0 + i) * d.C + (c0 + ttx)];
  __syncthreads();
#pragma unroll
  for (int i = tty; i < 32; i += 8)
    dst[(size_t)(c0 + i) * d.R + (r0 + ttx)] = f2bf(tile[ttx][i]);
}

// ---------------- grouped pipelined GEMM: C = relu(A @ B^T + bias) ----------------
// A: [4096][K] bf16; BT: [N][K] bf16; C: [4096][N] bf16.
// BM=256, BN=128, BK=64, 8 waves (4 M-strips x 2 N-strips), ring-3 LDS K-slots.
// T2 chunk-XOR swizzle (global-src pre-swizzle + swizzled ds_read), counted vmcnt(6).
struct GemmDesc {
  const u16* A;
  const u16* BT;
  const float* bias;
  u16* C;
  int K;
  int N;
};
struct GemmArgs { GemmDesc d[12]; };

__global__ __launch_bounds__(512) void k_gemm8(GemmArgs args) {
  __shared__ __align__(16) u16 As[3 * 16384];  // 3 slots x 256x64
  __shared__ __align__(16) u16 Bs[3 * 8192];   // 3 slots x 128x64

  GemmDesc g = args.d[blockIdx.y];
  const int K = g.K, N = g.N;
  const int ntN = N >> 7;
  const int lg = (ntN == 4) ? 2 : 1;
  const int bx = blockIdx.x;
  const int row0 = (bx >> lg) << 8;
  const int col0 = (bx & (ntN - 1)) << 7;

  const int tid = threadIdx.x;
  const int lane = tid & 63;
  const int wid = tid >> 6;
  const int wm = wid >> 1;  // 0..3: 64-row strip of 256
  const int wn = wid & 1;   // 0..1: 64-col strip of 128
  const int lrow = lane & 15;
  const int lkq = lane >> 4;      // 0..3
  const int sw = lrow & 7;        // swizzle key
  const int cx0 = lkq ^ sw;       // ksub=0 chunk-low-bits
  const int cx1 = (4 | lkq) ^ sw; // ksub=1

  int aoffs[4], boffs[4];
#pragma unroll
  for (int m = 0; m < 4; ++m) aoffs[m] = ((wm << 6) + (m << 4) + lrow) << 3;
#pragma unroll
  for (int n = 0; n < 4; ++n) boffs[n] = ((wn << 6) + (n << 4) + lrow) << 3;

  // staging: A slot = 2048 16B-chunks (256 rows x 8), B slot = 1024 chunks.
  // dest linear at chunk c; content = global (row=c>>3, gchunk=(c&7)^(row&7)).
  auto stageA = [&](int s, int kt, int j) {
    const int cb = (j << 9) + (wid << 6);
    const int c = cb + lane;
    const int r = c >> 3;
    const int gch = (c & 7) ^ (r & 7);
    GL2LDS16(g.A + (size_t)(row0 + r) * K + (kt << 6) + (gch << 3),
             &As[s * 16384 + cb * 8]);
  };
  auto stageB = [&](int s, int kt, int j) {
    const int cb = (j << 9) + (wid << 6);
    const int c = cb + lane;
    const int r = c >> 3;
    const int gch = (c & 7) ^ (r & 7);
    GL2LDS16(g.BT + (size_t)(col0 + r) * K + (kt << 6) + (gch << 3),
             &Bs[s * 8192 + cb * 8]);
  };

  f32x4 acc[4][4];
#pragma unroll
  for (int m = 0; m < 4; ++m)
#pragma unroll
    for (int n = 0; n < 4; ++n)
      acc[m][n] = (f32x4){0.f, 0.f, 0.f, 0.f};

  const int T = K >> 6;
  // prologue: stage tiles 0 and 1
#pragma unroll
  for (int j = 0; j < 4; ++j) stageA(0, 0, j);
#pragma unroll
  for (int j = 0; j < 2; ++j) stageB(0, 0, j);
#pragma unroll
  for (int j = 0; j < 4; ++j) stageA(1, 1, j);
#pragma unroll
  for (int j = 0; j < 2; ++j) stageB(1, 1, j);
  asm volatile("s_waitcnt vmcnt(6)" ::: "memory");
  __builtin_amdgcn_s_barrier();

  int slot = 0;
  for (int t = 0; t < T; ++t) {
    const u16* Asl = &As[slot * 16384];
    const u16* Bsl = &Bs[slot * 8192];
    const int s2 = (slot >= 1) ? slot - 1 : 2;  // (slot+2)%3
    short8 a[4], b[4];

    // ---- phase 0 (ksub 0) ----
#pragma unroll
    for (int m = 0; m < 4; ++m) a[m] = *(const short8*)&Asl[(aoffs[m] | cx0) << 3];
#pragma unroll
    for (int n = 0; n < 4; ++n) b[n] = *(const short8*)&Bsl[(boffs[n] | cx0) << 3];
    if (t + 2 < T) { stageA(s2, t + 2, 0); stageA(s2, t + 2, 1); stageB(s2, t + 2, 0); }
    __builtin_amdgcn_s_barrier();
    asm volatile("s_waitcnt lgkmcnt(0)" ::: "memory");
    __builtin_amdgcn_sched_barrier(0);
    __builtin_amdgcn_s_setprio(1);
#pragma unroll
    for (int m = 0; m < 4; ++m)
#pragma unroll
      for (int n = 0; n < 4; ++n)
        acc[m][n] = __builtin_amdgcn_mfma_f32_16x16x32_bf16(a[m], b[n], acc[m][n], 0, 0, 0);
    __builtin_amdgcn_s_setprio(0);
    __builtin_amdgcn_s_barrier();

    // ---- phase 1 (ksub 1) ----
#pragma unroll
    for (int m = 0; m < 4; ++m) a[m] = *(const short8*)&Asl[(aoffs[m] | cx1) << 3];
#pragma unroll
    for (int n = 0; n < 4; ++n) b[n] = *(const short8*)&Bsl[(boffs[n] | cx1) << 3];
    if (t + 2 < T) { stageA(s2, t + 2, 2); stageA(s2, t + 2, 3); stageB(s2, t + 2, 1); }
    __builtin_amdgcn_s_barrier();
    asm volatile("s_waitcnt lgkmcnt(0)" ::: "memory");
    __builtin_amdgcn_sched_barrier(0);
    __builtin_amdgcn_s_setprio(1);
#pragma unroll
    for (int m = 0; m < 4; ++m)
#pragma unroll
      for (int n = 0; n < 4; ++n)
        acc[m][n] = __builtin_amdgcn_mfma_f32_16x16x32_bf16(a[m], b[n], acc[m][n], 0, 0, 0);
    __builtin_amdgcn_s_setprio(0);
    asm volatile("s_waitcnt vmcnt(6)" ::: "memory");  // drains tile t+1's 6 loads
    __builtin_amdgcn_s_barrier();

    slot = (slot == 2) ? 0 : slot + 1;
  }

  // epilogue: bias + relu + bf16 store. C/D map: col=lane&15, row=(lane>>4)*4+j
  const int rb = lkq << 2;
#pragma unroll
  for (int n = 0; n < 4; ++n) {
    const int gc = col0 + (wn << 6) + (n << 4) + lrow;
    const float bv = g.bias[gc];
#pragma unroll
    for (int m = 0; m < 4; ++m) {
      const int gr = row0 + (wm << 6) + (m << 4) + rb;
#pragma unroll
      for (int j = 0; j < 4; ++j) {
        float o = fmaxf(acc[m][n][j] + bv, 0.f);
        g.C[(size_t)(gr + j) * N + gc] = f2bf(o);
      }
    }
  }
}

// ---------------- gated reduce: 3 outputs from 12 expert outputs ----------------
__global__ void k_reduce(const u16* __restrict__ OutB, const float* __restrict__ gsh,
                         const float* __restrict__ g1, const float* __restrict__ g2,
                         float* __restrict__ out) {
  int t = blockIdx.x * 256 + threadIdx.x;
  int b = t >> 5;
  int c0 = (t & 31) << 3;
  float wsh[12], w1[8], w2[8];
#pragma unroll
  for (int j = 0; j < 12; ++j) wsh[j] = gsh[(size_t)b * 12 + j];
#pragma unroll
  for (int j = 0; j < 8; ++j) { w1[j] = g1[(size_t)b * 8 + j]; w2[j] = g2[(size_t)b * 8 + j]; }
  float ash[8] = {0, 0, 0, 0, 0, 0, 0, 0};
  float a1[8] = {0, 0, 0, 0, 0, 0, 0, 0};
  float a2[8] = {0, 0, 0, 0, 0, 0, 0, 0};
#pragma unroll
  for (int e = 0; e < 12; ++e) {
    short8 v = *(const short8*)&OutB[((size_t)e * 4096 + b) * 256 + c0];
    float f[8];
#pragma unroll
    for (int i = 0; i < 8; ++i) f[i] = bf2f((u16)v[i]);
#pragma unroll
    for (int i = 0; i < 8; ++i) ash[i] += wsh[e] * f[i];
    if (e < 4) {
#pragma unroll
      for (int i = 0; i < 8; ++i) a1[i] += w1[e] * f[i];
    } else if (e < 8) {
#pragma unroll
      for (int i = 0; i < 8; ++i) a2[i] += w2[e - 4] * f[i];
    } else {
#pragma unroll
      for (int i = 0; i < 8; ++i) a1[i] += w1[e - 4] * f[i];
#pragma unroll
      for (int i = 0; i < 8; ++i) a2[i] += w2[e - 4] * f[i];
    }
  }
  size_t base = (size_t)b * 256 + c0;
  float4* o;
  o = (float4*)(out + base);
  o[0] = make_float4(ash[0], ash[1], ash[2], ash[3]);
  o[1] = make_float4(ash[4], ash[5], ash[6], ash[7]);
  o = (float4*)(out + 4096ull * 256 + base);
  o[0] = make_float4(a1[0], a1[1], a1[2], a1[3]);
  o[1] = make_float4(a1[4], a1[5], a1[6], a1[7]);
  o = (float4*)(out + 2ull * 4096 * 256 + base);
  o[0] = make_float4(a2[0], a2[1], a2[2], a2[3]);
  o[1] = make_float4(a2[4], a2[5], a2[6], a2[7]);
}

extern "C" void kernel_launch(void* const* d_in, const int* in_sizes, int n_in,
                              void* d_out, int out_size, void* d_ws, size_t ws_size,
                              hipStream_t stream) {
  const float* x_full = (const float*)d_in[0];
  const float* x_t1 = (const float*)d_in[1];
  const float* x_t2 = (const float*)d_in[2];
  const float* sh_W1 = (const float*)d_in[3];
  const float* sh_b1 = (const float*)d_in[4];
  const float* sh_W2 = (const float*)d_in[5];
  const float* sh_b2 = (const float*)d_in[6];
  const float* t1_W1 = (const float*)d_in[7];
  const float* t1_b1 = (const float*)d_in[8];
  const float* t1_W2 = (const float*)d_in[9];
  const float* t1_b2 = (const float*)d_in[10];
  const float* t2_W1 = (const float*)d_in[11];
  const float* t2_b1 = (const float*)d_in[12];
  const float* t2_W2 = (const float*)d_in[13];
  const float* t2_b2 = (const float*)d_in[14];
  const float* gsh_W = (const float*)d_in[15];
  const float* gsh_b = (const float*)d_in[16];
  const float* g1_W = (const float*)d_in[17];
  const float* g1_b = (const float*)d_in[18];
  const float* g2_W = (const float*)d_in[19];
  const float* g2_b = (const float*)d_in[20];

  char* ws = (char*)d_ws;
  size_t off = 0;
  auto alloc = [&](size_t bytes) -> void* {
    void* p = ws + off;
    off += (bytes + 255) & ~(size_t)255;
    return p;
  };
  u16* xf_b = (u16*)alloc(4096ull * 1024 * 2);
  u16* x1_b = (u16*)alloc(4096ull * 512 * 2);
  u16* x2_b = (u16*)alloc(4096ull * 512 * 2);
  u16* w1t_t1 = (u16*)alloc(4ull * 512 * 512 * 2);   // [e][HID=512][K=512]
  u16* w1t_t2 = (u16*)alloc(4ull * 512 * 512 * 2);
  u16* w1t_sh = (u16*)alloc(4ull * 512 * 1024 * 2);  // [e][512][1024]
  u16* w2t = (u16*)alloc(12ull * 256 * 512 * 2);     // [slot][OUT=256][HID=512]
  u16* H = (u16*)alloc(12ull * 4096 * 512 * 2);      // hidden, slots: t1 0-3, t2 4-7, sh 8-11
  u16* OutB = (u16*)alloc(12ull * 4096 * 256 * 2);   // expert outputs, same slot order
  float* gshv = (float*)alloc(4096ull * 12 * 4);
  float* g1v = (float*)alloc(4096ull * 8 * 4);
  float* g2v = (float*)alloc(4096ull * 8 * 4);

  // --- gates + x->bf16 (fused) ---
  k_gates_cvt<<<4096, 64, 0, stream>>>(x_full, x_t1, x_t2, gsh_W, gsh_b, g1_W, g1_b, g2_W, g2_b,
                                       xf_b, x1_b, x2_b, gshv, g1v, g2v);

  // --- weight transpose+convert, single launch ---
  TArgs ta;
  ta.d[0] = TD{t1_W1, w1t_t1, 8, 4, 512, 512, 0};
  ta.d[1] = TD{t2_W1, w1t_t2, 8, 4, 512, 512, 1024};
  ta.d[2] = TD{sh_W1, w1t_sh, 9, 4, 1024, 512, 2048};
  ta.d[3] = TD{t1_W2, w2t, 7, 3, 512, 256, 4096};
  ta.d[4] = TD{t2_W2, w2t + 4ull * 256 * 512, 7, 3, 512, 256, 4608};
  ta.d[5] = TD{sh_W2, w2t + 8ull * 256 * 512, 7, 3, 512, 256, 5120};
  k_transpose_all<<<5632, dim3(32, 8), 0, stream>>>(ta);

  // --- GEMM1: H = relu(x @ W1 + b1), grouped over 12 experts (shared first) ---
  GemmArgs ga1;
  for (int e = 0; e < 4; ++e) {
    ga1.d[e] = GemmDesc{xf_b, w1t_sh + (size_t)e * 512 * 1024, sh_b1 + e * 512,
                        H + (size_t)(8 + e) * 4096 * 512, 1024, 512};
    ga1.d[4 + e] = GemmDesc{x1_b, w1t_t1 + (size_t)e * 512 * 512, t1_b1 + e * 512,
                            H + (size_t)e * 4096 * 512, 512, 512};
    ga1.d[8 + e] = GemmDesc{x2_b, w1t_t2 + (size_t)e * 512 * 512, t2_b1 + e * 512,
                            H + (size_t)(4 + e) * 4096 * 512, 512, 512};
  }
  k_gemm8<<<dim3(64, 12), 512, 0, stream>>>(ga1);

  // --- GEMM2: Out = relu(H @ W2 + b2), grouped over 12 experts ---
  GemmArgs ga2;
  for (int e = 0; e < 12; ++e) {
    const float* bias = (e < 4) ? (t1_b2 + e * 256)
                      : (e < 8) ? (t2_b2 + (e - 4) * 256)
                                : (sh_b2 + (e - 8) * 256);
    ga2.d[e] = GemmDesc{H + (size_t)e * 4096 * 512, w2t + (size_t)e * 256 * 512, bias,
                        OutB + (size_t)e * 4096 * 256, 512, 256};
  }
  k_gemm8<<<dim3(32, 12), 512, 0, stream>>>(ga2);

  // --- gated reduce -> d_out (out_sh | out1 | out2), fp32 ---
  k_reduce<<<512, 256, 0, stream>>>(OutB, gshv, g1v, g2v, (float*)d_out);
}

// Round 3
// 113.162 us; speedup vs baseline: 1.1588x; 1.0415x over previous
//
#include <hip/hip_runtime.h>

typedef unsigned short u16;
typedef __attribute__((ext_vector_type(8))) short short8;
typedef __attribute__((ext_vector_type(4))) float f32x4;

#define GL2LDS16(src, dst) __builtin_amdgcn_global_load_lds( \
    (const __attribute__((address_space(1))) void*)(src),    \
    (__attribute__((address_space(3))) void*)(dst), 16, 0, 0)

__device__ __forceinline__ u16 f2bf(float f) {
  union { float f; unsigned u; } v; v.f = f;
  unsigned r = v.u + 0x7fffu + ((v.u >> 16) & 1u);
  return (u16)(r >> 16);
}
__device__ __forceinline__ float bf2f(u16 h) {
  union { unsigned u; float f; } v; v.u = ((unsigned)h) << 16; return v.f;
}

// ---------------- gates + x->bf16 conversion, one wave per row ----------------
__global__ void k_gates_cvt(const float* __restrict__ xf, const float* __restrict__ x1,
                            const float* __restrict__ x2,
                            const float* __restrict__ gshW, const float* __restrict__ gshB,
                            const float* __restrict__ g1W, const float* __restrict__ g1B,
                            const float* __restrict__ g2W, const float* __restrict__ g2B,
                            u16* __restrict__ xfb, u16* __restrict__ x1b, u16* __restrict__ x2b,
                            float* __restrict__ gsh, float* __restrict__ g1o,
                            float* __restrict__ g2o) {
  const int b = blockIdx.x, lane = threadIdx.x;
  float s[12];
#pragma unroll
  for (int j = 0; j < 12; ++j) s[j] = 0.f;
  {
    const float* xr = xf + (size_t)b * 1024;
    u16* xw = xfb + (size_t)b * 1024;
    for (int k = lane; k < 1024; k += 64) {
      float v = xr[k];
      xw[k] = f2bf(v);
      const float* wr = gshW + (size_t)k * 12;
#pragma unroll
      for (int j = 0; j < 12; ++j) s[j] += v * wr[j];
    }
  }
  float u[8], w[8];
#pragma unroll
  for (int j = 0; j < 8; ++j) { u[j] = 0.f; w[j] = 0.f; }
  {
    const float* xr1 = x1 + (size_t)b * 512;
    const float* xr2 = x2 + (size_t)b * 512;
    u16* xw1 = x1b + (size_t)b * 512;
    u16* xw2 = x2b + (size_t)b * 512;
    for (int k = lane; k < 512; k += 64) {
      float v1 = xr1[k], v2 = xr2[k];
      xw1[k] = f2bf(v1); xw2[k] = f2bf(v2);
      const float* w1r = g1W + (size_t)k * 8;
      const float* w2r = g2W + (size_t)k * 8;
#pragma unroll
      for (int j = 0; j < 8; ++j) { u[j] += v1 * w1r[j]; w[j] += v2 * w2r[j]; }
    }
  }
#pragma unroll
  for (int off = 32; off >= 1; off >>= 1) {
#pragma unroll
    for (int j = 0; j < 12; ++j) s[j] += __shfl_xor(s[j], off, 64);
#pragma unroll
    for (int j = 0; j < 8; ++j) { u[j] += __shfl_xor(u[j], off, 64); w[j] += __shfl_xor(w[j], off, 64); }
  }
  if (lane == 0) {
    float m = -1e30f, tot = 0.f;
#pragma unroll
    for (int j = 0; j < 12; ++j) { s[j] += gshB[j]; m = fmaxf(m, s[j]); }
#pragma unroll
    for (int j = 0; j < 12; ++j) { s[j] = __expf(s[j] - m); tot += s[j]; }
    float inv = 1.f / tot;
#pragma unroll
    for (int j = 0; j < 12; ++j) gsh[(size_t)b * 12 + j] = s[j] * inv;
    m = -1e30f; tot = 0.f;
#pragma unroll
    for (int j = 0; j < 8; ++j) { u[j] += g1B[j]; m = fmaxf(m, u[j]); }
#pragma unroll
    for (int j = 0; j < 8; ++j) { u[j] = __expf(u[j] - m); tot += u[j]; }
    inv = 1.f / tot;
#pragma unroll
    for (int j = 0; j < 8; ++j) g1o[(size_t)b * 8 + j] = u[j] * inv;
    m = -1e30f; tot = 0.f;
#pragma unroll
    for (int j = 0; j < 8; ++j) { w[j] += g2B[j]; m = fmaxf(m, w[j]); }
#pragma unroll
    for (int j = 0; j < 8; ++j) { w[j] = __expf(w[j] - m); tot += w[j]; }
    inv = 1.f / tot;
#pragma unroll
    for (int j = 0; j < 8; ++j) g2o[(size_t)b * 8 + j] = w[j] * inv;
  }
}

// ------------- merged weight transpose+convert: fp32 [z][R][C] -> bf16 [z][C][R] -------------
struct TD { const float* src; u16* dst; int lgTps; int lgNtx; int R; int C; int tileBase; };
struct TArgs { TD d[6]; };

__global__ void k_transpose_all(TArgs ta) {
  __shared__ float tile[32][33];
  const int x = blockIdx.x;
  int di = 0;
#pragma unroll
  for (int i = 1; i < 6; ++i)
    if (x >= ta.d[i].tileBase) di = i;
  TD d = ta.d[di];
  const int local = x - d.tileBase;
  const int slice = local >> d.lgTps;
  const int ti = local & ((1 << d.lgTps) - 1);
  const int tx = ti & ((1 << d.lgNtx) - 1);
  const int ty = ti >> d.lgNtx;
  const float* src = d.src + (size_t)slice * d.R * d.C;
  u16* dst = d.dst + (size_t)slice * d.R * d.C;
  const int c0 = tx * 32, r0 = ty * 32;
  const int ttx = threadIdx.x, tty = threadIdx.y;
#pragma unroll
  for (int i = tty; i < 32; i += 8)
    tile[i][ttx] = src[(size_t)(r0 + i) * d.C + (c0 + ttx)];
  __syncthreads();
#pragma unroll
  for (int i = tty; i < 32; i += 8)
    dst[(size_t)(c0 + i) * d.R + (r0 + ttx)] = f2bf(tile[ttx][i]);
}

// ---------------- grouped 256x256 8-phase GEMM: C = relu(A @ B^T + bias) ----------------
// A: [4096][K] bf16; BT: [N][K] bf16; C: [4096][N] bf16.  BM=BN=256, BK=64.
// 8 waves (2M x 4N), wave tile 128x64, acc[8][4]. 8 phases / 2 K-tiles,
// phase = (tile, ksub, Mhalf), 16 MFMA/phase, b-frag reuse on Mhalf=1 phases.
// LDS: A 2buf x 2Mhalf x [128][64]; B 2buf x 2ksub x [256][32]. 128 KiB.
// Swizzle (rule 21, both-sides): A chunk^= (r&7); B chunk^= ((r>>1)&3).
struct GemmDesc {
  const u16* A;
  const u16* BT;
  const float* bias;
  u16* C;
  int K;
  int N;
  int iters;  // K/128
};
struct GemmArgs { GemmDesc d[12]; };

#define PHASE(BUF, KS, MH, ...)                                                   \
  {                                                                               \
    const char* AsB = (const char*)As + (BUF) * 32768;                            \
    const char* BsB = (const char*)Bs + (BUF) * 32768 + (KS) * 16384;             \
    if ((MH) == 0) {                                                              \
      _Pragma("unroll") for (int ni = 0; ni < 4; ++ni)                            \
          b[ni] = *(const short8*)(BsB + boff[ni]);                               \
    }                                                                             \
    _Pragma("unroll") for (int q = 0; q < 4; ++q)                                 \
        a[q] = *(const short8*)(AsB + (aoff[(MH) * 4 + q] ^ ((KS) * 64)));        \
    __VA_ARGS__;                                                                  \
    __builtin_amdgcn_s_barrier();                                                 \
    asm volatile("s_waitcnt lgkmcnt(0)" ::: "memory");                            \
    __builtin_amdgcn_sched_barrier(0);                                            \
    __builtin_amdgcn_s_setprio(1);                                                \
    _Pragma("unroll") for (int q = 0; q < 4; ++q)                                 \
        _Pragma("unroll") for (int ni = 0; ni < 4; ++ni)                          \
            acc[(MH) * 4 + q][ni] = __builtin_amdgcn_mfma_f32_16x16x32_bf16(      \
                a[q], b[ni], acc[(MH) * 4 + q][ni], 0, 0, 0);                     \
    __builtin_amdgcn_s_setprio(0);                                                \
  }

__global__ __launch_bounds__(512, 1) void k_gemm256(GemmArgs args) {
  __shared__ __align__(16) u16 As[32768];  // 2buf x 2half x 128 x 64
  __shared__ __align__(16) u16 Bs[32768];  // 2buf x 2ksub x 256 x 32

  GemmDesc g = args.d[blockIdx.y];
  const int K = g.K, N = g.N, iters = g.iters;
  const int ntN = N >> 8;                 // 2 (GEMM1) or 1 (GEMM2)
  const int lg = (ntN == 2) ? 1 : 0;
  const int bx = blockIdx.x;
  const int row0 = (bx >> lg) << 8;
  const int col0 = (bx & (ntN - 1)) << 8;

  const int tid = threadIdx.x;
  const int lane = tid & 63;
  const int wid = tid >> 6;
  const int wm = wid & 1;    // 2 M-strips of 128
  const int wn = wid >> 1;   // 4 N-strips of 64
  const int lrow = lane & 15;
  const int lkq = lane >> 4;  // 0..3

  // ds_read byte offsets
  int aoff[8], boff[4];
#pragma unroll
  for (int mi = 0; mi < 8; ++mi)
    aoff[mi] = wm * 16384 + (mi * 16 + lrow) * 128 + ((lkq ^ (lrow & 7)) * 16);
#pragma unroll
  for (int ni = 0; ni < 4; ++ni)
    boff[ni] = (wn * 64 + ni * 16 + lrow) * 64 + ((lkq ^ ((lrow >> 1) & 3)) * 16);

  // staging helpers: linear LDS dest, pre-swizzled global source
  auto stageAhalf = [&](int buf, int half, int kt) {
#pragma unroll
    for (int j = 0; j < 2; ++j) {
      const int cb = (wid * 2 + j) * 64;
      const int c = cb + lane;
      const int r = c >> 3;
      const int cir = (c & 7) ^ (r & 7);
      GL2LDS16(g.A + (size_t)(row0 + half * 128 + r) * K + kt * 64 + cir * 8,
               &As[(buf * 2048 + half * 1024 + cb) * 8]);
    }
  };
  auto stageBhalf = [&](int buf, int ks, int kt) {
#pragma unroll
    for (int j = 0; j < 2; ++j) {
      const int cb = (wid * 2 + j) * 64;
      const int c = cb + lane;
      const int r = c >> 2;
      const int cir = (c & 3) ^ ((r >> 1) & 3);
      GL2LDS16(g.BT + (size_t)(col0 + r) * K + kt * 64 + ks * 32 + cir * 8,
               &Bs[(buf * 2048 + ks * 1024 + cb) * 8]);
    }
  };

  f32x4 acc[8][4];
#pragma unroll
  for (int m = 0; m < 8; ++m)
#pragma unroll
    for (int n = 0; n < 4; ++n)
      acc[m][n] = (f32x4){0.f, 0.f, 0.f, 0.f};

  // prologue: buf0 <- tile 0 (all 4 half-tiles), buf1 <- tile 1 (B only)
  stageBhalf(0, 0, 0); stageBhalf(0, 1, 0);
  stageAhalf(0, 0, 0); stageAhalf(0, 1, 0);
  stageBhalf(1, 0, 1); stageBhalf(1, 1, 1);
  asm volatile("s_waitcnt vmcnt(4)" ::: "memory");
  __builtin_amdgcn_s_barrier();

  short8 a[4], b[4];
  for (int i = 0; i < iters; ++i) {
    const int t1 = 2 * i + 1;
    const bool nl = (i + 1 < iters);
    PHASE(0, 0, 0, stageAhalf(1, 0, t1));
    __builtin_amdgcn_s_barrier();
    PHASE(0, 0, 1, stageAhalf(1, 1, t1));
    __builtin_amdgcn_s_barrier();
    PHASE(0, 1, 0, if (nl) stageBhalf(0, 0, t1 + 1));
    __builtin_amdgcn_s_barrier();
    PHASE(0, 1, 1, if (nl) stageBhalf(0, 1, t1 + 1));
    if (nl) { asm volatile("s_waitcnt vmcnt(4)" ::: "memory"); }
    else    { asm volatile("s_waitcnt vmcnt(0)" ::: "memory"); }
    __builtin_amdgcn_s_barrier();
    PHASE(1, 0, 0, if (nl) stageAhalf(0, 0, t1 + 1));
    __builtin_amdgcn_s_barrier();
    PHASE(1, 0, 1, if (nl) stageAhalf(0, 1, t1 + 1));
    __builtin_amdgcn_s_barrier();
    PHASE(1, 1, 0, if (nl) stageBhalf(1, 0, t1 + 2));
    __builtin_amdgcn_s_barrier();
    PHASE(1, 1, 1, if (nl) stageBhalf(1, 1, t1 + 2));
    asm volatile("s_waitcnt vmcnt(4)" ::: "memory");
    __builtin_amdgcn_s_barrier();
  }

  // epilogue: bias + relu + bf16 store. C/D map: col=lane&15, row=(lane>>4)*4+j
#pragma unroll
  for (int ni = 0; ni < 4; ++ni) {
    const int gc = col0 + wn * 64 + ni * 16 + lrow;
    const float bv = g.bias[gc];
#pragma unroll
    for (int mi = 0; mi < 8; ++mi) {
      const int gr = row0 + wm * 128 + mi * 16 + lkq * 4;
#pragma unroll
      for (int j = 0; j < 4; ++j) {
        float o = fmaxf(acc[mi][ni][j] + bv, 0.f);
        g.C[(size_t)(gr + j) * N + gc] = f2bf(o);
      }
    }
  }
}

// ---------------- gated reduce: 3 outputs from 12 expert outputs ----------------
__global__ void k_reduce(const u16* __restrict__ OutB, const float* __restrict__ gsh,
                         const float* __restrict__ g1, const float* __restrict__ g2,
                         float* __restrict__ out) {
  int t = blockIdx.x * 256 + threadIdx.x;
  int b = t >> 5;
  int c0 = (t & 31) << 3;
  float wsh[12], w1[8], w2[8];
#pragma unroll
  for (int j = 0; j < 12; ++j) wsh[j] = gsh[(size_t)b * 12 + j];
#pragma unroll
  for (int j = 0; j < 8; ++j) { w1[j] = g1[(size_t)b * 8 + j]; w2[j] = g2[(size_t)b * 8 + j]; }
  float ash[8] = {0, 0, 0, 0, 0, 0, 0, 0};
  float a1[8] = {0, 0, 0, 0, 0, 0, 0, 0};
  float a2[8] = {0, 0, 0, 0, 0, 0, 0, 0};
#pragma unroll
  for (int e = 0; e < 12; ++e) {
    short8 v = *(const short8*)&OutB[((size_t)e * 4096 + b) * 256 + c0];
    float f[8];
#pragma unroll
    for (int i = 0; i < 8; ++i) f[i] = bf2f((u16)v[i]);
#pragma unroll
    for (int i = 0; i < 8; ++i) ash[i] += wsh[e] * f[i];
    if (e < 4) {
#pragma unroll
      for (int i = 0; i < 8; ++i) a1[i] += w1[e] * f[i];
    } else if (e < 8) {
#pragma unroll
      for (int i = 0; i < 8; ++i) a2[i] += w2[e - 4] * f[i];
    } else {
#pragma unroll
      for (int i = 0; i < 8; ++i) a1[i] += w1[e - 4] * f[i];
#pragma unroll
      for (int i = 0; i < 8; ++i) a2[i] += w2[e - 4] * f[i];
    }
  }
  size_t base = (size_t)b * 256 + c0;
  float4* o;
  o = (float4*)(out + base);
  o[0] = make_float4(ash[0], ash[1], ash[2], ash[3]);
  o[1] = make_float4(ash[4], ash[5], ash[6], ash[7]);
  o = (float4*)(out + 4096ull * 256 + base);
  o[0] = make_float4(a1[0], a1[1], a1[2], a1[3]);
  o[1] = make_float4(a1[4], a1[5], a1[6], a1[7]);
  o = (float4*)(out + 2ull * 4096 * 256 + base);
  o[0] = make_float4(a2[0], a2[1], a2[2], a2[3]);
  o[1] = make_float4(a2[4], a2[5], a2[6], a2[7]);
}

extern "C" void kernel_launch(void* const* d_in, const int* in_sizes, int n_in,
                              void* d_out, int out_size, void* d_ws, size_t ws_size,
                              hipStream_t stream) {
  const float* x_full = (const float*)d_in[0];
  const float* x_t1 = (const float*)d_in[1];
  const float* x_t2 = (const float*)d_in[2];
  const float* sh_W1 = (const float*)d_in[3];
  const float* sh_b1 = (const float*)d_in[4];
  const float* sh_W2 = (const float*)d_in[5];
  const float* sh_b2 = (const float*)d_in[6];
  const float* t1_W1 = (const float*)d_in[7];
  const float* t1_b1 = (const float*)d_in[8];
  const float* t1_W2 = (const float*)d_in[9];
  const float* t1_b2 = (const float*)d_in[10];
  const float* t2_W1 = (const float*)d_in[11];
  const float* t2_b1 = (const float*)d_in[12];
  const float* t2_W2 = (const float*)d_in[13];
  const float* t2_b2 = (const float*)d_in[14];
  const float* gsh_W = (const float*)d_in[15];
  const float* gsh_b = (const float*)d_in[16];
  const float* g1_W = (const float*)d_in[17];
  const float* g1_b = (const float*)d_in[18];
  const float* g2_W = (const float*)d_in[19];
  const float* g2_b = (const float*)d_in[20];

  char* ws = (char*)d_ws;
  size_t off = 0;
  auto alloc = [&](size_t bytes) -> void* {
    void* p = ws + off;
    off += (bytes + 255) & ~(size_t)255;
    return p;
  };
  u16* xf_b = (u16*)alloc(4096ull * 1024 * 2);
  u16* x1_b = (u16*)alloc(4096ull * 512 * 2);
  u16* x2_b = (u16*)alloc(4096ull * 512 * 2);
  u16* w1t_t1 = (u16*)alloc(4ull * 512 * 512 * 2);   // [e][HID=512][K=512]
  u16* w1t_t2 = (u16*)alloc(4ull * 512 * 512 * 2);
  u16* w1t_sh = (u16*)alloc(4ull * 512 * 1024 * 2);  // [e][512][1024]
  u16* w2t = (u16*)alloc(12ull * 256 * 512 * 2);     // [slot][OUT=256][HID=512]
  u16* H = (u16*)alloc(12ull * 4096 * 512 * 2);      // hidden, slots: t1 0-3, t2 4-7, sh 8-11
  u16* OutB = (u16*)alloc(12ull * 4096 * 256 * 2);   // expert outputs, same slot order
  float* gshv = (float*)alloc(4096ull * 12 * 4);
  float* g1v = (float*)alloc(4096ull * 8 * 4);
  float* g2v = (float*)alloc(4096ull * 8 * 4);

  // --- gates + x->bf16 (fused) ---
  k_gates_cvt<<<4096, 64, 0, stream>>>(x_full, x_t1, x_t2, gsh_W, gsh_b, g1_W, g1_b, g2_W, g2_b,
                                       xf_b, x1_b, x2_b, gshv, g1v, g2v);

  // --- weight transpose+convert, single launch ---
  TArgs ta;
  ta.d[0] = TD{t1_W1, w1t_t1, 8, 4, 512, 512, 0};
  ta.d[1] = TD{t2_W1, w1t_t2, 8, 4, 512, 512, 1024};
  ta.d[2] = TD{sh_W1, w1t_sh, 9, 4, 1024, 512, 2048};
  ta.d[3] = TD{t1_W2, w2t, 7, 3, 512, 256, 4096};
  ta.d[4] = TD{t2_W2, w2t + 4ull * 256 * 512, 7, 3, 512, 256, 4608};
  ta.d[5] = TD{sh_W2, w2t + 8ull * 256 * 512, 7, 3, 512, 256, 5120};
  k_transpose_all<<<5632, dim3(32, 8), 0, stream>>>(ta);

  // --- GEMM1: H = relu(x @ W1 + b1), grouped over 12 experts (shared K=1024 first) ---
  GemmArgs ga1;
  for (int e = 0; e < 4; ++e) {
    ga1.d[e] = GemmDesc{xf_b, w1t_sh + (size_t)e * 512 * 1024, sh_b1 + e * 512,
                        H + (size_t)(8 + e) * 4096 * 512, 1024, 512, 8};
    ga1.d[4 + e] = GemmDesc{x1_b, w1t_t1 + (size_t)e * 512 * 512, t1_b1 + e * 512,
                            H + (size_t)e * 4096 * 512, 512, 512, 4};
    ga1.d[8 + e] = GemmDesc{x2_b, w1t_t2 + (size_t)e * 512 * 512, t2_b1 + e * 512,
                            H + (size_t)(4 + e) * 4096 * 512, 512, 512, 4};
  }
  k_gemm256<<<dim3(32, 12), 512, 0, stream>>>(ga1);

  // --- GEMM2: Out = relu(H @ W2 + b2), grouped over 12 experts ---
  GemmArgs ga2;
  for (int e = 0; e < 12; ++e) {
    const float* bias = (e < 4) ? (t1_b2 + e * 256)
                      : (e < 8) ? (t2_b2 + (e - 4) * 256)
                                : (sh_b2 + (e - 8) * 256);
    ga2.d[e] = GemmDesc{H + (size_t)e * 4096 * 512, w2t + (size_t)e * 256 * 512, bias,
                        OutB + (size_t)e * 4096 * 256, 512, 256, 4};
  }
  k_gemm256<<<dim3(16, 12), 512, 0, stream>>>(ga2);

  // --- gated reduce -> d_out (out_sh | out1 | out2), fp32 ---
  k_reduce<<<512, 256, 0, stream>>>(OutB, gshv, g1v, g2v, (float*)d_out);
}